// Round 8
// baseline (334.629 us; speedup 1.0000x reference)
//
#include <hip/hip_runtime.h>
#include <stdint.h>

#define B_  4
#define S_  2048
#define D_  768
#define H_  12
#define DH_ 64
#define DF_ 2048
#define M_  (B_*S_)   // 8192
#define NQKV 2304
#define N13  4096

typedef __attribute__((ext_vector_type(8))) short bf16x8;
typedef __attribute__((ext_vector_type(4))) short bf16x4;
typedef __attribute__((ext_vector_type(4))) float f32x4;
typedef unsigned short u16;

// K=16 bf16 MFMA. __has_builtin for amdgcn builtins is FALSE in the host pass,
// so probe only under __HIP_DEVICE_COMPILE__; host just needs it to typecheck.
#if !defined(__HIP_DEVICE_COMPILE__)
  #define MFMA_K16(A,B,C) (C)
#elif __has_builtin(__builtin_amdgcn_mfma_f32_16x16x16_bf16)
  #define MFMA_K16(A,B,C) __builtin_amdgcn_mfma_f32_16x16x16_bf16((A),(B),(C),0,0,0)
#else
  #define MFMA_K16(A,B,C) __builtin_amdgcn_mfma_f32_16x16x16bf16_1k((A),(B),(C),0,0,0)
#endif

__device__ __forceinline__ float bf2f(u16 v) {
  union { uint32_t u; float f; } x; x.u = ((uint32_t)v) << 16; return x.f;
}
__device__ __forceinline__ u16 f2bf(float f) {
  union { float f; uint32_t u; } x; x.f = f;
  uint32_t r = x.u + 0x7FFFu + ((x.u >> 16) & 1u);
  return (u16)(r >> 16);
}
// async global->LDS, 16B per lane; LDS dest is wave-uniform base + lane*16
__device__ __forceinline__ void gl_lds16(const u16* g, u16* l) {
  __builtin_amdgcn_global_load_lds((const __attribute__((address_space(1))) uint32_t*)g,
                                   (__attribute__((address_space(3))) uint32_t*)l, 16, 0, 0);
}

// ---------------- fused cast fp32 -> bf16 for pq/pk/pv/po/w2 (1 launch) ----------
__global__ __launch_bounds__(256) void cast_all_kernel(const float* __restrict__ pq,
                                                       const float* __restrict__ pk,
                                                       const float* __restrict__ pv,
                                                       const float* __restrict__ po,
                                                       const float* __restrict__ w2,
                                                       u16* __restrict__ wqkv,
                                                       u16* __restrict__ wob,
                                                       u16* __restrict__ w2b) {
  int bidx = blockIdx.x;
  const float* src; u16* dst; int off;
  if (bidx < 576)       { src = pq; dst = wqkv;           off = bidx; }
  else if (bidx < 1152) { src = pk; dst = wqkv + 589824;  off = bidx - 576; }
  else if (bidx < 1728) { src = pv; dst = wqkv + 1179648; off = bidx - 1152; }
  else if (bidx < 2304) { src = po; dst = wob;            off = bidx - 1728; }
  else                  { src = w2; dst = w2b;            off = bidx - 2304; }
  int i = off * 256 + threadIdx.x;
  float4 v = ((const float4*)src)[i];
  ushort4 o;
  o.x = f2bf(v.x); o.y = f2bf(v.y); o.z = f2bf(v.z); o.w = f2bf(v.w);
  ((ushort4*)dst)[i] = o;
}

// ---------------- cast w1/w3 into 16-row interleaved fused layout ----------------
__global__ __launch_bounds__(192) void cast_w13_kernel(const float* __restrict__ w1,
                                                       const float* __restrict__ w3,
                                                       u16* __restrict__ out) {
  int j = blockIdx.x, which = blockIdx.y;
  const float* src = (which ? w3 : w1) + (size_t)j * D_;
  int fr = (j >> 4) * 32 + (j & 15) + which * 16;
  u16* dst = out + (size_t)fr * D_;
  int t = threadIdx.x;
  float4 v = ((const float4*)src)[t];
  ushort4 o;
  o.x = f2bf(v.x); o.y = f2bf(v.y); o.z = f2bf(v.z); o.w = f2bf(v.w);
  ((ushort4*)dst)[t] = o;
}

// ---------------- RMSNorm: fp32 in -> bf16 out ----------------
__global__ __launch_bounds__(256) void rmsnorm_kernel(const float* __restrict__ x,
                                                      const float* __restrict__ w,
                                                      u16* __restrict__ out) {
  int row = blockIdx.x, tid = threadIdx.x;
  const float* xr = x + (size_t)row * D_;
  float v0 = xr[tid], v1 = xr[tid + 256], v2 = xr[tid + 512];
  float ss = v0 * v0 + v1 * v1 + v2 * v2;
  #pragma unroll
  for (int m = 32; m >= 1; m >>= 1) ss += __shfl_xor(ss, m, 64);
  __shared__ float red[4];
  if ((tid & 63) == 0) red[tid >> 6] = ss;
  __syncthreads();
  float tot = red[0] + red[1] + red[2] + red[3];
  float r = rsqrtf(tot * (1.0f / D_) + 1e-5f);
  u16* o = out + (size_t)row * D_;
  o[tid]       = f2bf(v0 * r * w[tid]);
  o[tid + 256] = f2bf(v1 * r * w[tid + 256]);
  o[tid + 512] = f2bf(v2 * r * w[tid + 512]);
}

// ---------------- GEMM: C[M,N] = A[M,K] * W[N,K]^T  (m97 + XOR-swizzled LDS) ------
// LDS swizzle comes FREE with global_load_lds by permuting the global source
// chunk (c ^ (r&7)) — frag ds_read_b128 conflict-free.
// R7: bijective XCD-chunk block swizzle (grid blocks %8==0 REQUIRED). Each XCD
// owns a contiguous lin-range executed row-major: its L2 holds full B (<=3.5MB)
// + current 128-row A-panel (196KB) -> main-loop loads become L2 hits.
// EPI 0: bf16. EPI 1: fp32 = acc+res. EPI 2: silu-pair -> g[M,N/2].
// EPI 3: QKV epilogue — RoPE in-register (shfl pair exchange + __sincosf),
//        v blocks transposed through LDS for coalesced vT writes.
template<int MT, int EPI>
__global__ __launch_bounds__(256) void gemm_bt_kernel(const u16* __restrict__ A,
                                                      const u16* __restrict__ W,
                                                      void* __restrict__ Cout,
                                                      const float* __restrict__ res,
                                                      u16* __restrict__ vTout,
                                                      int K, int N) {
  constexpr int ABELEMS = MT * 64 + 128 * 64;
  constexpr int SMELEMS = (EPI == 3 && 128 * 132 > ABELEMS) ? 128 * 132 : ABELEMS;
  __shared__ __align__(16) u16 smem[SMELEMS];
  u16* As = smem;
  u16* Bs = smem + MT * 64;
  constexpr int MI = MT / 32;
  int tid = threadIdx.x;
  int wave = tid >> 6, lane = tid & 63;
  int quad = lane >> 4, l16 = lane & 15;
  int wr = (wave >> 1) * (MT / 2), wc = (wave & 1) * 64;
  // XCD-chunk swizzle: lin%8 = XCD slot; chunk executes row-major (x fastest)
  int gx = gridDim.x;
  int lin = blockIdx.y * gx + blockIdx.x;
  int cpx = (gx * gridDim.y) >> 3;             // blocks per XCD chunk
  int nlin = (lin & 7) * cpx + (lin >> 3);
  int m0 = (nlin / gx) * MT, n0 = (nlin % gx) * 128;
  f32x4 acc[MI][4] = {};
  for (int kt = 0; kt < K; kt += 64) {
    __syncthreads();
    #pragma unroll
    for (int i = 0; i < MT / 32; ++i) {
      int idx = i * 256 + tid;
      int r = idx >> 3, c = idx & 7;
      gl_lds16(&A[(size_t)(m0 + r) * K + kt + ((c ^ (r & 7)) * 8)], &As[(i * 256 + wave * 64) * 8]);
    }
    #pragma unroll
    for (int i = 0; i < 4; ++i) {
      int idx = i * 256 + tid;
      int r = idx >> 3, c = idx & 7;
      gl_lds16(&W[(size_t)(n0 + r) * K + kt + ((c ^ (r & 7)) * 8)], &Bs[(i * 256 + wave * 64) * 8]);
    }
    __syncthreads();
    #pragma unroll
    for (int ks = 0; ks < 2; ++ks) {
      bf16x8 af[MI], bf[4];
      int sw = ((ks * 4 + quad) ^ (l16 & 7)) * 8;   // swizzled chunk offset (u16)
      #pragma unroll
      for (int t = 0; t < MI; ++t)
        af[t] = *(const bf16x8*)&As[(wr + t * 16 + l16) * 64 + sw];
      #pragma unroll
      for (int t = 0; t < 4; ++t)
        bf[t] = *(const bf16x8*)&Bs[(wc + t * 16 + l16) * 64 + sw];
      #pragma unroll
      for (int mt = 0; mt < MI; ++mt)
        #pragma unroll
        for (int nt = 0; nt < 4; ++nt)
          acc[mt][nt] = __builtin_amdgcn_mfma_f32_16x16x32_bf16(af[mt], bf[nt], acc[mt][nt], 0, 0, 0);
    }
  }

  if (EPI == 3 && n0 >= 1536) {
    // ---- v blocks: 128x128 tile -> LDS (stride 132) -> coalesced vT stores ----
    __syncthreads();   // other waves may still be reading As/Bs frags
    #pragma unroll
    for (int mt = 0; mt < MI; ++mt) {
      int sloc = wr + mt * 16 + quad * 4;
      #pragma unroll
      for (int nt = 0; nt < 4; ++nt) {
        int col = wc + nt * 16 + l16;
        ushort4 o;
        o.x = f2bf(acc[mt][nt][0]); o.y = f2bf(acc[mt][nt][1]);
        o.z = f2bf(acc[mt][nt][2]); o.w = f2bf(acc[mt][nt][3]);
        *(ushort4*)&smem[col * 132 + sloc] = o;
      }
    }
    __syncthreads();
    int b = m0 >> 11, sblk = m0 & 2047;
    #pragma unroll
    for (int i = 0; i < 8; ++i) {
      int idx = i * 256 + tid;           // 0..2047: 128 rows x 16 chunks
      int row = idx >> 4, c16 = idx & 15;
      uint4 d = *(const uint4*)&smem[row * 132 + c16 * 8];
      int vg = n0 - 1536 + row;
      int h = vg >> 6, dh = vg & 63;
      *(uint4*)&vTout[((size_t)(b * H_ + h) * 64 + dh) * (size_t)S_ + sblk + c16 * 8] = d;
    }
  } else if (EPI == 3) {
    // ---- q/k blocks: RoPE in-register (pair = adjacent lane), then store ----
    bool isq = (n0 < 768);
    float osc = isq ? 0.18033688f : 1.0f;   // q: 1/sqrt(64) * log2(e)
    #pragma unroll
    for (int mt = 0; mt < MI; ++mt) {
      int r0 = m0 + wr + mt * 16 + quad * 4;
      int pos0 = r0 & 2047;
      #pragma unroll
      for (int nt = 0; nt < 4; ++nt) {
        int col = n0 + wc + nt * 16 + l16;
        int kk = (col & 63) >> 1;
        float freq = exp2f(-0.41524101186092035f * (float)kk);
        bool odd = (col & 1);
        #pragma unroll
        for (int r = 0; r < 4; ++r) {
          float own = acc[mt][nt][r];
          float pv = __shfl_xor(own, 1, 64);
          float ang = (float)(pos0 + r) * freq;
          float sv, cv;
          __sincosf(ang, &sv, &cv);
          float o = odd ? (sv * pv + cv * own) : (cv * own - sv * pv);
          ((u16*)Cout)[(size_t)(r0 + r) * N + col] = f2bf(o * osc);
        }
      }
    }
  } else {
    #pragma unroll
    for (int mt = 0; mt < MI; ++mt) {
      #pragma unroll
      for (int r = 0; r < 4; ++r) {
        int gr = m0 + wr + mt * 16 + quad * 4 + r;
        if (EPI == 2) {
          #pragma unroll
          for (int np = 0; np < 2; ++np) {
            float u1v = acc[mt][np * 2][r], u3v = acc[mt][np * 2 + 1][r];
            float sg = 1.0f / (1.0f + __builtin_amdgcn_exp2f(-u1v * 1.44269504f));
            float g = u1v * sg * u3v;
            int gc = (n0 >> 1) + (wave & 1) * 32 + np * 16 + l16;
            ((u16*)Cout)[(size_t)gr * (N >> 1) + gc] = f2bf(g);
          }
        } else {
          #pragma unroll
          for (int nt = 0; nt < 4; ++nt) {
            int gc = n0 + wc + nt * 16 + l16;
            size_t off = (size_t)gr * N + gc;
            float vv = acc[mt][nt][r];
            if (EPI == 1) ((float*)Cout)[off] = vv + res[off];
            else          ((u16*)Cout)[off] = f2bf(vv);
          }
        }
      }
    }
  }
}

// ================= 256x256 8-phase GEMM (T2+T3+T4+T5, m201 structure) ============
// C[M,N] = A[M,K] * W[N,K]^T, bf16 in. K,N compile-time (reg-pressure control).
// 8 waves (2M x 4N); per-wave output 128x64 = acc[2][4][2][2] (mh,mt,nh,nt).
// LDS: smem[buf][A/B][half][128x64] = 128 KiB, swizzle via permuted global src.
// R2 pressure fix (R1 spilled): K/N template constants; 32-bit running
// voffsets; SINGLE A-frag buffer (reload after MFMA, covered by next phase's
// lgkmcnt(0)); last iteration peeled. R4: bijective XCD-chunk swizzle.
// R8: PERSISTENT 2-TILE blocks — grid = NB/2 = 256 (1 block/CU, no dispatch
// tail); each block runs two tiles back-to-back in the same swizzled order.
// Tile-2's 8-STG prologue is issued AFTER tile-1's final barrier (all LDS
// reads provably retired: every ds_read completes at an lgkmcnt(0) >=1
// barrier before the end of the last iteration) and BEFORE tile-1's epilogue
// (register+global only, no LDS) -> 128KiB staging latency hides under the
// SiLU/store epilogue. Tile-2 entry: vmcnt(0) (staging+epilogue stores
// drained) + barrier, replacing the cold serial prologue of generation 2.
// Schedule per iteration (tiles t0=2i,t1=2i+1; stage t2,t3):
//   ph1: rd t0.B1->rBhi | st t2.A0 | Q00 |
//   ph2:                | st t2.B0 | Q01 | rd t0.A1->rA
//   ph3:                | st t2.B1 | Q10 | vmcnt(6)
//   ph4: rd t1.B0->rBlo | st t2.A1 | Q11 | rd t1.A0->rA
//   ph5: rd t1.B1->rBhi | st t3.A0 | Q00 |
//   ph6:                | st t3.B0 | Q01 | rd t1.A1->rA
//   ph7:                | st t3.B1 | Q10 | vmcnt(6)
//   ph8: rd t2.B0->rBlo | st t3.A1 | Q11 | rd t2.A0->rA
// vmcnt(6) leaves the 3 newest half-tiles (6 loads) in flight.
#define FENCE() asm volatile("" ::: "memory")
#define BAR() do { FENCE(); __builtin_amdgcn_s_barrier(); FENCE(); } while (0)
#define LGKM0() do { asm volatile("s_waitcnt lgkmcnt(0)" ::: "memory"); \
                     __builtin_amdgcn_sched_barrier(0); } while (0)

template<int MH, int NH>
__device__ __forceinline__ void quad_mfma(f32x4 (&acc)[2][4][2][2],
                                          const bf16x8 (&ra)[4][2],
                                          const bf16x8 (&rb)[2][2]) {
  #pragma unroll
  for (int ks = 0; ks < 2; ++ks)
    #pragma unroll
    for (int mt = 0; mt < 4; ++mt)
      #pragma unroll
      for (int nt = 0; nt < 2; ++nt)
        acc[MH][mt][NH][nt] =
          __builtin_amdgcn_mfma_f32_16x16x32_bf16(ra[mt][ks], rb[nt][ks], acc[MH][mt][NH][nt], 0, 0, 0);
}

__device__ __forceinline__ void ld_af(bf16x8 (&rr)[4][2], const u16* base,
                                      int wrow, int l16, int quad) {
  #pragma unroll
  for (int mt = 0; mt < 4; ++mt)
    #pragma unroll
    for (int ks = 0; ks < 2; ++ks)
      rr[mt][ks] = *(const bf16x8*)&base[(wrow + mt * 16 + l16) * 64 +
                                         (((ks * 4 + quad) ^ (l16 & 7)) * 8)];
}
__device__ __forceinline__ void ld_bf(bf16x8 (&rr)[2][2], const u16* base,
                                      int wrow, int l16, int quad) {
  #pragma unroll
  for (int nt = 0; nt < 2; ++nt)
    #pragma unroll
    for (int ks = 0; ks < 2; ++ks)
      rr[nt][ks] = *(const bf16x8*)&base[(wrow + nt * 16 + l16) * 64 +
                                         (((ks * 4 + quad) ^ (l16 & 7)) * 8)];
}

template<int EPI, int K, int N>
__global__ __launch_bounds__(512, 2) void gemm256_kernel(const u16* __restrict__ A,
                                                         const u16* __restrict__ W,
                                                         void* __restrict__ Cout,
                                                         const float* __restrict__ res) {
  __shared__ __align__(16) u16 smem[2][2][2][128 * 64];   // [buf][A/B][half] = 128 KiB
  int tid = threadIdx.x;
  int wave = tid >> 6, lane = tid & 63;
  int quad = lane >> 4, l16 = lane & 15;
  int wm = wave >> 2, wn = wave & 3;
  constexpr int GX = N / 256, NB = GX * (M_ / 256), CPX = NB / 8, HB = NB / 2;
  constexpr int NI = (K >> 6) >> 1;   // tile-pairs; K%128==0, NI>=2
  int bid = blockIdx.x;               // [0, HB)

  // staging: 2 loads/thread per half-tile; r0=tid>>3 row, c0=tid&7 chunk
  int r0 = tid >> 3, c0 = tid & 7;
  int scb = (c0 ^ (r0 & 7)) * 16;                       // swizzled chunk, bytes
  int wrA = wm * 64, wrB = wn * 32;

  // kof: 0 = tile t2 (even, buf0), 128 = tile t3 (odd, buf1); h adds 128 rows.
  #define STG(kof, ab, h, bufi) do {                                               \
    const char* _s = (ab) ? (const char*)W : (const char*)A;                       \
    uint32_t _o = ((ab) ? offB : offA) + (uint32_t)((kof) + (h) * (128 * K * 2));  \
    u16* _d = &smem[bufi][ab][h][wave * 512];                                      \
    gl_lds16((const u16*)(_s + _o), _d);                                           \
    gl_lds16((const u16*)(_s + _o + 64 * K * 2), _d + 4096);                       \
  } while (0)

  #define STG_T01() do {                                                           \
    STG(0, 0, 0, 0); STG(0, 1, 0, 0); STG(0, 1, 1, 0); STG(0, 0, 1, 0);            \
    STG(128, 0, 0, 1); STG(128, 1, 0, 1); STG(128, 1, 1, 1); STG(128, 0, 1, 1);    \
  } while (0)

  #pragma unroll 1
  for (int s = 0; s < 2; ++s) {
    // XCD-chunk swizzle (bijective): lin%8 = XCD slot; same tile order as the
    // original 2-generation dispatch (block bid handles lin = bid and HB+bid).
    int lin = s * HB + bid;
    int nlin = (lin & 7) * CPX + (lin >> 3);
    int m0 = (nlin / GX) * 256, n0 = (nlin % GX) * 256;
    uint32_t offA = (uint32_t)(m0 + r0) * (uint32_t)(K * 2) + (uint32_t)scb;
    uint32_t offB = (uint32_t)(n0 + r0) * (uint32_t)(K * 2) + (uint32_t)scb;

    f32x4 acc[2][4][2][2] = {};
    bf16x8 rA[4][2], rBlo[2][2], rBhi[2][2];

    if (s == 0) {
      // ---- cold prologue: stage t0 {A0,B0,B1,A1}, t1 {A0,B0,B1,A1} ----
      STG_T01();
      asm volatile("s_waitcnt vmcnt(8)" ::: "memory");   // t0 fully landed
    } else {
      // tile-2 t0/t1 were staged during tile-1's epilogue lead; epilogue
      // stores + staging all drained here.
      asm volatile("s_waitcnt vmcnt(0)" ::: "memory");
    }
    offA += 256; offB += 256;                          // now points at t2
    BAR();
    ld_af(rA,   &smem[0][0][0][0], wrA, l16, quad);    // t0.A0
    ld_bf(rBlo, &smem[0][1][0][0], wrB, l16, quad);    // t0.B0
    LGKM0();
    BAR();                                             // reads done before ph1 stage

    #define G256_ITER(MORE) do {                                                     \
      /* ph1: Q00 */                                                                 \
      ld_bf(rBhi, &smem[0][1][1][0], wrB, l16, quad);                                \
      if (MORE) STG(0, 0, 0, 0);                                                     \
      BAR(); LGKM0();                                                                \
      __builtin_amdgcn_s_setprio(1); quad_mfma<0, 0>(acc, rA, rBlo);                 \
      __builtin_amdgcn_s_setprio(0); BAR();                                          \
      /* ph2: Q01, then rA <- t0.A1 */                                               \
      if (MORE) STG(0, 1, 0, 0);                                                     \
      BAR(); LGKM0();                                                                \
      __builtin_amdgcn_s_setprio(1); quad_mfma<0, 1>(acc, rA, rBhi);                 \
      __builtin_amdgcn_s_setprio(0);                                                 \
      ld_af(rA, &smem[0][0][1][0], wrA, l16, quad);                                  \
      BAR();                                                                         \
      /* ph3: Q10 | vmcnt drains t1 */                                               \
      if (MORE) STG(0, 1, 1, 0);                                                     \
      BAR(); LGKM0();                                                                \
      __builtin_amdgcn_s_setprio(1); quad_mfma<1, 0>(acc, rA, rBlo);                 \
      __builtin_amdgcn_s_setprio(0);                                                 \
      if (MORE) asm volatile("s_waitcnt vmcnt(6)" ::: "memory");                     \
      else      asm volatile("s_waitcnt vmcnt(0)" ::: "memory");                     \
      BAR();                                                                         \
      /* ph4: Q11, rBlo <- t1.B0, then rA <- t1.A0 */                                \
      ld_bf(rBlo, &smem[1][1][0][0], wrB, l16, quad);                                \
      if (MORE) STG(0, 0, 1, 0);                                                     \
      BAR(); LGKM0();                                                                \
      __builtin_amdgcn_s_setprio(1); quad_mfma<1, 1>(acc, rA, rBhi);                 \
      __builtin_amdgcn_s_setprio(0);                                                 \
      ld_af(rA, &smem[1][0][0][0], wrA, l16, quad);                                  \
      BAR();                                                                         \
      /* ph5: Q00 (t1) */                                                            \
      ld_bf(rBhi, &smem[1][1][1][0], wrB, l16, quad);                                \
      if (MORE) STG(128, 0, 0, 1);                                                   \
      BAR(); LGKM0();                                                                \
      __builtin_amdgcn_s_setprio(1); quad_mfma<0, 0>(acc, rA, rBlo);                 \
      __builtin_amdgcn_s_setprio(0); BAR();                                          \
      /* ph6: Q01, then rA <- t1.A1 */                                               \
      if (MORE) STG(128, 1, 0, 1);                                                   \
      BAR(); LGKM0();                                                                \
      __builtin_amdgcn_s_setprio(1); quad_mfma<0, 1>(acc, rA, rBhi);                 \
      __builtin_amdgcn_s_setprio(0);                                                 \
      ld_af(rA, &smem[1][0][1][0], wrA, l16, quad);                                  \
      BAR();                                                                         \
      /* ph7: Q10 | vmcnt drains t2 */                                               \
      if (MORE) STG(128, 1, 1, 1);                                                   \
      BAR(); LGKM0();                                                                \
      __builtin_amdgcn_s_setprio(1); quad_mfma<1, 0>(acc, rA, rBlo);                 \
      __builtin_amdgcn_s_setprio(0);                                                 \
      if (MORE) asm volatile("s_waitcnt vmcnt(6)" ::: "memory");                     \
      else      asm volatile("s_waitcnt vmcnt(0)" ::: "memory");                     \
      BAR();                                                                         \
      /* ph8: Q11, rBlo <- t2.B0, then rA <- t2.A0 */                                \
      if (MORE) ld_bf(rBlo, &smem[0][1][0][0], wrB, l16, quad);                      \
      if (MORE) STG(128, 0, 1, 1);                                                   \
      BAR(); LGKM0();                                                                \
      __builtin_amdgcn_s_setprio(1); quad_mfma<1, 1>(acc, rA, rBhi);                 \
      __builtin_amdgcn_s_setprio(0);                                                 \
      if (MORE) ld_af(rA, &smem[0][0][0][0], wrA, l16, quad);                        \
      BAR();                                                                         \
    } while (0)

    #pragma unroll 1
    for (int i = 0; i < NI - 1; ++i) {
      G256_ITER(true);
      offA += 256; offB += 256;
    }
    G256_ITER(false);
    #undef G256_ITER

    if (s == 0) {
      // ---- epilogue lead: stage tile-2's t0/t1 now; latency hides under the
      // epilogue below. Safe: all LDS reads retired >=1 barrier ago (final
      // BAR of last iteration), epilogue touches no LDS. ----
      int lin2 = HB + bid;
      int nlin2 = (lin2 & 7) * CPX + (lin2 >> 3);
      offA = (uint32_t)((nlin2 / GX) * 256 + r0) * (uint32_t)(K * 2) + (uint32_t)scb;
      offB = (uint32_t)((nlin2 % GX) * 256 + r0) * (uint32_t)(K * 2) + (uint32_t)scb;
      STG_T01();
    }

    // ---- epilogue (register + global only; no LDS) ----
    if (EPI == 2) {
      const int Nh = N >> 1;
      #pragma unroll
      for (int mh = 0; mh < 2; ++mh)
        #pragma unroll
        for (int mt = 0; mt < 4; ++mt)
          #pragma unroll
          for (int r = 0; r < 4; ++r) {
            int gr = m0 + mh * 128 + wm * 64 + mt * 16 + quad * 4 + r;
            #pragma unroll
            for (int nh = 0; nh < 2; ++nh) {
              float u1v = acc[mh][mt][nh][0][r], u3v = acc[mh][mt][nh][1][r];
              float sg = 1.0f / (1.0f + __builtin_amdgcn_exp2f(-u1v * 1.44269504f));
              float g = u1v * sg * u3v;
              int gc = (n0 >> 1) + nh * 64 + wn * 16 + l16;
              ((u16*)Cout)[(size_t)gr * Nh + gc] = f2bf(g);
            }
          }
    } else if (EPI == 1) {
      #pragma unroll
      for (int mh = 0; mh < 2; ++mh)
        #pragma unroll
        for (int mt = 0; mt < 4; ++mt)
          #pragma unroll
          for (int r = 0; r < 4; ++r) {
            int gr = m0 + mh * 128 + wm * 64 + mt * 16 + quad * 4 + r;
            #pragma unroll
            for (int nh = 0; nh < 2; ++nh)
              #pragma unroll
              for (int nt = 0; nt < 2; ++nt) {
                int gc = n0 + nh * 128 + wn * 32 + nt * 16 + l16;
                size_t off = (size_t)gr * N + gc;
                ((float*)Cout)[off] = acc[mh][mt][nh][nt][r] + res[off];
              }
          }
    } else {
      #pragma unroll
      for (int mh = 0; mh < 2; ++mh)
        #pragma unroll
        for (int mt = 0; mt < 4; ++mt)
          #pragma unroll
          for (int r = 0; r < 4; ++r) {
            int gr = m0 + mh * 128 + wm * 64 + mt * 16 + quad * 4 + r;
            #pragma unroll
            for (int nh = 0; nh < 2; ++nh)
              #pragma unroll
              for (int nt = 0; nt < 2; ++nt) {
                int gc = n0 + nh * 128 + wn * 32 + nt * 16 + l16;
                ((u16*)Cout)[(size_t)gr * N + gc] = f2bf(acc[mh][mt][nh][nt][r]);
              }
          }
    }
  }
  #undef STG_T01
  #undef STG
}

// ---------------- Flash attention (causal), S^T formulation, no P round-trip ------
// S^T = mfma(kf, qf) -> C-layout: key=quad*4+r, query=l16. Packed bf16 of those
// 4 regs IS the B-frag (k=quad*4+j) of a K=16 MFMA, so PV = mfma_16x16x16(vf, pf).
// Staging via global_load_lds with source-permuted chunks (same swizzle as reads).
// R3: 512-thread / 8-wave blocks, wave owns 16 queries (was 256/4w/32q).
// grid: (48 bh, 16 qt descending). block 512.
__global__ __launch_bounds__(512, 4) void attn_kernel(const u16* __restrict__ qkv,
                                                      const u16* __restrict__ vT,
                                                      u16* __restrict__ ctx) {
  __shared__ __align__(16) u16 Ks[128 * 64];   // [key][dh], physical chunk = c ^ (key&7)
  __shared__ __align__(16) u16 Vt[64 * 128];   // [dh][key], physical chunk = c ^ (dh&15)
  int bh = blockIdx.x;
  int qt = 15 - blockIdx.y;                    // LPT: biggest tiles first
  int b = bh / H_, h = bh % H_;
  const u16* qbase = qkv + (size_t)b * S_ * NQKV + h * DH_;
  const u16* kbase = qbase + 768;
  const u16* vtb   = vT + (size_t)bh * 64 * S_;
  int tid = threadIdx.x, wave = tid >> 6, lane = tid & 63;
  int quad = lane >> 4, l16 = lane & 15;
  const float MFIX = 12.0f;

  bf16x8 qf[2];
  int qrow = qt * 128 + wave * 16 + l16;
  qf[0] = *(const bf16x8*)&qbase[(size_t)qrow * NQKV + quad * 8];
  qf[1] = *(const bf16x8*)&qbase[(size_t)qrow * NQKV + 32 + quad * 8];
  f32x4 oacc[4] = {};
  float lsum = 0.f;
  int nkt = qt + 1;
  for (int kt = 0; kt < nkt; ++kt) {
    __syncthreads();
    // async staging; source chunk permuted so LDS lands pre-swizzled
    #pragma unroll
    for (int i = 0; i < 2; ++i) {
      int idx = i * 512 + tid;
      int r = idx >> 3, c = idx & 7;
      gl_lds16(&kbase[(size_t)(kt * 128 + r) * NQKV + ((c ^ (r & 7)) * 8)],
               &Ks[(i * 512 + wave * 64) * 8]);
    }
    #pragma unroll
    for (int i = 0; i < 2; ++i) {
      int idx = i * 512 + tid;
      int d = idx >> 4, c16 = idx & 15;
      gl_lds16(&vtb[(size_t)d * S_ + kt * 128 + ((c16 ^ (d & 15)) * 8)],
               &Vt[(i * 512 + wave * 64) * 8]);
    }
    __syncthreads();
    bool diag = (kt == nkt - 1);
    #pragma unroll
    for (int t = 0; t < 8; ++t) {
      if (diag && t > wave) break;   // fully-masked sub-tiles (wave-uniform)
      // S^T tile t: keys t*16..t*16+15 x 16 queries
      f32x4 sc = {};
      #pragma unroll
      for (int c = 0; c < 2; ++c) {
        bf16x8 kf = *(const bf16x8*)&Ks[(t * 16 + l16) * 64 + (((c * 4 + quad) ^ (l16 & 7)) * 8)];
        sc = __builtin_amdgcn_mfma_f32_16x16x32_bf16(kf, qf[c], sc, 0, 0, 0);
      }
      // exp2(s - MFIX), causal zeroing, per-lane l accumulation, bf16 pack
      float p[4];
      #pragma unroll
      for (int r = 0; r < 4; ++r) p[r] = __builtin_amdgcn_exp2f(sc[r] - MFIX);
      if (diag && t == wave) {
        #pragma unroll
        for (int r = 0; r < 4; ++r)
          if (quad * 4 + r > l16) p[r] = 0.f;
      }
      lsum += (p[0] + p[1]) + (p[2] + p[3]);
      uint32_t lo = ((__float_as_uint(p[0]) + 0x8000u) >> 16) |
                    ((__float_as_uint(p[1]) + 0x8000u) & 0xFFFF0000u);
      uint32_t hi = ((__float_as_uint(p[2]) + 0x8000u) >> 16) |
                    ((__float_as_uint(p[3]) + 0x8000u) & 0xFFFF0000u);
      uint2 pk; pk.x = lo; pk.y = hi;
      bf16x4 pf = *(bf16x4*)&pk;
      // PV: D[dh][query] += V^T-frag * P^T-frag, K=16
      #pragma unroll
      for (int n = 0; n < 4; ++n) {
        bf16x4 vf = *(const bf16x4*)&Vt[(n * 16 + l16) * 128 +
                                        (((t * 2 + (quad >> 1)) ^ l16) * 8) + (quad & 1) * 4];
        oacc[n] = MFMA_K16(vf, pf, oacc[n]);
      }
    }
  }
  // normalize: full l per query = reduce over the 4 quads holding its keys
  float l = lsum;
  l += __shfl_xor(l, 16, 64);
  l += __shfl_xor(l, 32, 64);
  float inv = 1.0f / l;
  #pragma unroll
  for (int n = 0; n < 4; ++n) {
    ushort4 o;
    o.x = f2bf(oacc[n][0] * inv);
    o.y = f2bf(oacc[n][1] * inv);
    o.z = f2bf(oacc[n][2] * inv);
    o.w = f2bf(oacc[n][3] * inv);
    *(ushort4*)&ctx[(size_t)(b * S_ + qrow) * D_ + h * DH_ + n * 16 + quad * 4] = o;
  }
}

// ---------------- workspace layout (bytes) ----------------
#define WQKV_OFF 0u            // 2304x768 bf16 = 3538944
#define W13_OFF  3538944u      // 4096x768 bf16 = 6291456 (interleaved)
#define W2_OFF   9830400u      // 768x2048 bf16 = 3145728
#define WO_OFF   12976128u     // 768x768 bf16  = 1179648
#define HB_OFF   14155776u     // 8192x768 bf16 = 12582912  (later: ctx)
#define QKV_OFF  26738688u     // 8192x2304 bf16 = 37748736
#define VT_OFF   64487424u     // 48x64x2048 bf16 = 12582912 (later: h2)
#define X1_OFF   77070336u     // 8192x768 fp32 = 25165824
#define G_OFF    102236160u    // 8192x2048 bf16 = 33554432 -> end 135790592

extern "C" void kernel_launch(void* const* d_in, const int* in_sizes, int n_in,
                              void* d_out, int out_size, void* d_ws, size_t ws_size,
                              hipStream_t stream) {
  const float* x    = (const float*)d_in[0];
  const float* ln1w = (const float*)d_in[1];
  const float* ln2w = (const float*)d_in[2];
  const float* pq   = (const float*)d_in[3];
  const float* pk   = (const float*)d_in[4];
  const float* pv   = (const float*)d_in[5];
  const float* po   = (const float*)d_in[6];
  const float* w1   = (const float*)d_in[7];
  const float* w2   = (const float*)d_in[8];
  const float* w3   = (const float*)d_in[9];
  char* ws = (char*)d_ws;
  u16* wqkv = (u16*)(ws + WQKV_OFF);
  u16* w13b = (u16*)(ws + W13_OFF);
  u16* w2b  = (u16*)(ws + W2_OFF);
  u16* wob  = (u16*)(ws + WO_OFF);
  u16* hb   = (u16*)(ws + HB_OFF);
  u16* qkvb = (u16*)(ws + QKV_OFF);
  u16* vtb  = (u16*)(ws + VT_OFF);
  u16* cb   = (u16*)(ws + HB_OFF);   // alias hb (dead after QKV GEMM)
  float* x1 = (float*)(ws + X1_OFF);
  u16* h2b  = (u16*)(ws + VT_OFF);   // alias vT (dead after attn)
  u16* gb   = (u16*)(ws + G_OFF);

  // weights -> bf16 (2 launches)
  cast_all_kernel<<<3840, 256, 0, stream>>>(pq, pk, pv, po, w2, wqkv, wob, w2b);
  cast_w13_kernel<<<dim3(2048, 2), 192, 0, stream>>>(w1, w3, w13b);

  // attention sublayer
  rmsnorm_kernel<<<M_, 256, 0, stream>>>(x, ln1w, hb);
  // QKV GEMM: R3 epilogue (fastest measured) + XCD swizzle (R7)
  gemm_bt_kernel<128, 3><<<dim3(18, 64), 256, 0, stream>>>(hb, wqkv, qkvb, nullptr, vtb, 768, NQKV);
  // attn: 8-wave blocks (R3 occupancy fix: was 4-wave, 18% occupancy)
  attn_kernel<<<dim3(48, 16), 512, 0, stream>>>(qkvb, vtb, cb);
  gemm_bt_kernel<64, 1><<<dim3(6, 128), 256, 0, stream>>>(cb, wob, x1, x, nullptr, 768, 768);

  // FFN sublayer
  rmsnorm_kernel<<<M_, 256, 0, stream>>>(x1, ln2w, h2b);
  // W13 GEMM: 256x256 8-phase + XCD swizzle; R8 persistent 2-tile (grid = 256)
  gemm256_kernel<2, 768, N13><<<dim3((N13 / 256) * (M_ / 256) / 2), 512, 0, stream>>>(h2b, w13b, gb, nullptr);
  gemm_bt_kernel<64, 1><<<dim3(6, 128), 256, 0, stream>>>(gb, w2b, (float*)d_out, x1, nullptr, 2048, 768);
}

// Round 10
// 319.472 us; speedup vs baseline: 1.0474x; 1.0474x over previous
//
#include <hip/hip_runtime.h>
#include <stdint.h>

#define B_  4
#define S_  2048
#define D_  768
#define H_  12
#define DH_ 64
#define DF_ 2048
#define M_  (B_*S_)   // 8192
#define NQKV 2304
#define N13  4096

typedef __attribute__((ext_vector_type(8))) short bf16x8;
typedef __attribute__((ext_vector_type(4))) short bf16x4;
typedef __attribute__((ext_vector_type(4))) float f32x4;
typedef unsigned short u16;

// K=16 bf16 MFMA. __has_builtin for amdgcn builtins is FALSE in the host pass,
// so probe only under __HIP_DEVICE_COMPILE__; host just needs it to typecheck.
#if !defined(__HIP_DEVICE_COMPILE__)
  #define MFMA_K16(A,B,C) (C)
#elif __has_builtin(__builtin_amdgcn_mfma_f32_16x16x16_bf16)
  #define MFMA_K16(A,B,C) __builtin_amdgcn_mfma_f32_16x16x16_bf16((A),(B),(C),0,0,0)
#else
  #define MFMA_K16(A,B,C) __builtin_amdgcn_mfma_f32_16x16x16bf16_1k((A),(B),(C),0,0,0)
#endif

__device__ __forceinline__ float bf2f(u16 v) {
  union { uint32_t u; float f; } x; x.u = ((uint32_t)v) << 16; return x.f;
}
__device__ __forceinline__ u16 f2bf(float f) {
  union { float f; uint32_t u; } x; x.f = f;
  uint32_t r = x.u + 0x7FFFu + ((x.u >> 16) & 1u);
  return (u16)(r >> 16);
}
// async global->LDS, 16B per lane; LDS dest is wave-uniform base + lane*16
__device__ __forceinline__ void gl_lds16(const u16* g, u16* l) {
  __builtin_amdgcn_global_load_lds((const __attribute__((address_space(1))) uint32_t*)g,
                                   (__attribute__((address_space(3))) uint32_t*)l, 16, 0, 0);
}

// ---------------- fused cast fp32 -> bf16 for pq/pk/pv/po/w2 (1 launch) ----------
__global__ __launch_bounds__(256) void cast_all_kernel(const float* __restrict__ pq,
                                                       const float* __restrict__ pk,
                                                       const float* __restrict__ pv,
                                                       const float* __restrict__ po,
                                                       const float* __restrict__ w2,
                                                       u16* __restrict__ wqkv,
                                                       u16* __restrict__ wob,
                                                       u16* __restrict__ w2b) {
  int bidx = blockIdx.x;
  const float* src; u16* dst; int off;
  if (bidx < 576)       { src = pq; dst = wqkv;           off = bidx; }
  else if (bidx < 1152) { src = pk; dst = wqkv + 589824;  off = bidx - 576; }
  else if (bidx < 1728) { src = pv; dst = wqkv + 1179648; off = bidx - 1152; }
  else if (bidx < 2304) { src = po; dst = wob;            off = bidx - 1728; }
  else                  { src = w2; dst = w2b;            off = bidx - 2304; }
  int i = off * 256 + threadIdx.x;
  float4 v = ((const float4*)src)[i];
  ushort4 o;
  o.x = f2bf(v.x); o.y = f2bf(v.y); o.z = f2bf(v.z); o.w = f2bf(v.w);
  ((ushort4*)dst)[i] = o;
}

// ---------------- cast w1/w3 into 16-row interleaved fused layout ----------------
__global__ __launch_bounds__(192) void cast_w13_kernel(const float* __restrict__ w1,
                                                       const float* __restrict__ w3,
                                                       u16* __restrict__ out) {
  int j = blockIdx.x, which = blockIdx.y;
  const float* src = (which ? w3 : w1) + (size_t)j * D_;
  int fr = (j >> 4) * 32 + (j & 15) + which * 16;
  u16* dst = out + (size_t)fr * D_;
  int t = threadIdx.x;
  float4 v = ((const float4*)src)[t];
  ushort4 o;
  o.x = f2bf(v.x); o.y = f2bf(v.y); o.z = f2bf(v.z); o.w = f2bf(v.w);
  ((ushort4*)dst)[t] = o;
}

// ---------------- RMSNorm: fp32 in -> bf16 out ----------------
__global__ __launch_bounds__(256) void rmsnorm_kernel(const float* __restrict__ x,
                                                      const float* __restrict__ w,
                                                      u16* __restrict__ out) {
  int row = blockIdx.x, tid = threadIdx.x;
  const float* xr = x + (size_t)row * D_;
  float v0 = xr[tid], v1 = xr[tid + 256], v2 = xr[tid + 512];
  float ss = v0 * v0 + v1 * v1 + v2 * v2;
  #pragma unroll
  for (int m = 32; m >= 1; m >>= 1) ss += __shfl_xor(ss, m, 64);
  __shared__ float red[4];
  if ((tid & 63) == 0) red[tid >> 6] = ss;
  __syncthreads();
  float tot = red[0] + red[1] + red[2] + red[3];
  float r = rsqrtf(tot * (1.0f / D_) + 1e-5f);
  u16* o = out + (size_t)row * D_;
  o[tid]       = f2bf(v0 * r * w[tid]);
  o[tid + 256] = f2bf(v1 * r * w[tid + 256]);
  o[tid + 512] = f2bf(v2 * r * w[tid + 512]);
}

// ---------------- GEMM: C[M,N] = A[M,K] * W[N,K]^T  (m97 + XOR-swizzled LDS) ------
// LDS swizzle comes FREE with global_load_lds by permuting the global source
// chunk (c ^ (r&7)) — frag ds_read_b128 conflict-free.
// R7: bijective XCD-chunk block swizzle (grid blocks %8==0 REQUIRED).
// EPI 1: fp32 = acc+res (O-proj, W2). Other EPIs retained but unused here.
template<int MT, int EPI>
__global__ __launch_bounds__(256) void gemm_bt_kernel(const u16* __restrict__ A,
                                                      const u16* __restrict__ W,
                                                      void* __restrict__ Cout,
                                                      const float* __restrict__ res,
                                                      u16* __restrict__ vTout,
                                                      int K, int N) {
  constexpr int ABELEMS = MT * 64 + 128 * 64;
  __shared__ __align__(16) u16 smem[ABELEMS];
  u16* As = smem;
  u16* Bs = smem + MT * 64;
  constexpr int MI = MT / 32;
  int tid = threadIdx.x;
  int wave = tid >> 6, lane = tid & 63;
  int quad = lane >> 4, l16 = lane & 15;
  int wr = (wave >> 1) * (MT / 2), wc = (wave & 1) * 64;
  // XCD-chunk swizzle: lin%8 = XCD slot; chunk executes row-major (x fastest)
  int gx = gridDim.x;
  int lin = blockIdx.y * gx + blockIdx.x;
  int cpx = (gx * gridDim.y) >> 3;             // blocks per XCD chunk
  int nlin = (lin & 7) * cpx + (lin >> 3);
  int m0 = (nlin / gx) * MT, n0 = (nlin % gx) * 128;
  f32x4 acc[MI][4] = {};
  for (int kt = 0; kt < K; kt += 64) {
    __syncthreads();
    #pragma unroll
    for (int i = 0; i < MT / 32; ++i) {
      int idx = i * 256 + tid;
      int r = idx >> 3, c = idx & 7;
      gl_lds16(&A[(size_t)(m0 + r) * K + kt + ((c ^ (r & 7)) * 8)], &As[(i * 256 + wave * 64) * 8]);
    }
    #pragma unroll
    for (int i = 0; i < 4; ++i) {
      int idx = i * 256 + tid;
      int r = idx >> 3, c = idx & 7;
      gl_lds16(&W[(size_t)(n0 + r) * K + kt + ((c ^ (r & 7)) * 8)], &Bs[(i * 256 + wave * 64) * 8]);
    }
    __syncthreads();
    #pragma unroll
    for (int ks = 0; ks < 2; ++ks) {
      bf16x8 af[MI], bf[4];
      int sw = ((ks * 4 + quad) ^ (l16 & 7)) * 8;   // swizzled chunk offset (u16)
      #pragma unroll
      for (int t = 0; t < MI; ++t)
        af[t] = *(const bf16x8*)&As[(wr + t * 16 + l16) * 64 + sw];
      #pragma unroll
      for (int t = 0; t < 4; ++t)
        bf[t] = *(const bf16x8*)&Bs[(wc + t * 16 + l16) * 64 + sw];
      #pragma unroll
      for (int mt = 0; mt < MI; ++mt)
        #pragma unroll
        for (int nt = 0; nt < 4; ++nt)
          acc[mt][nt] = __builtin_amdgcn_mfma_f32_16x16x32_bf16(af[mt], bf[nt], acc[mt][nt], 0, 0, 0);
    }
  }

  #pragma unroll
  for (int mt = 0; mt < MI; ++mt) {
    #pragma unroll
    for (int r = 0; r < 4; ++r) {
      int gr = m0 + wr + mt * 16 + quad * 4 + r;
      #pragma unroll
      for (int nt = 0; nt < 4; ++nt) {
        int gc = n0 + wc + nt * 16 + l16;
        size_t off = (size_t)gr * N + gc;
        float vv = acc[mt][nt][r];
        if (EPI == 1) ((float*)Cout)[off] = vv + res[off];
        else          ((u16*)Cout)[off] = f2bf(vv);
      }
    }
  }
}

// ================= 256x256 8-phase GEMM (T2+T3+T4+T5, m201 structure) ============
// C[M,N] = A[M,K] * W[N,K]^T, bf16 in. K,N compile-time (reg-pressure control).
// 8 waves (2M x 4N); per-wave output 128x64 = acc[2][4][2][2] (mh,mt,nh,nt).
// LDS: smem[buf][A/B][half][128x64] = 128 KiB, swizzle via permuted global src.
// R2 pressure fix (R1 spilled): K/N template constants; 32-bit running
// voffsets; SINGLE A-frag buffer (reload after MFMA, covered by next phase's
// lgkmcnt(0)); last iteration peeled. R4: bijective XCD-chunk swizzle.
// R9: R8's persistent 2-tile REVERTED (spilled: WRITE 34.8->53.2MB, acc
// pushed past the 256-reg cliff by loop-carried tile state; main loop
// tolerates ZERO extra live state). Grid back to one tile per block.
// EPI 2: silu-pair -> g[M,N/2]  (W13).
// EPI 3: QKV — q/k tiles (n0<1536): RoPE in-register (same math as the
//   measured-best R3 epilogue; shfl_xor(own,1) pair exchange, col&63 =
//   (wn&1)*32+nt*16+l16 so parity = l16&1, freq hoisted per nt, sincos
//   hoisted over nh). v tiles (n0>=1536, exactly tiles 6-8): two-pass
//   256x128 LDS transpose (stride 132, 67.6KB of smem, reused after the
//   final barrier) -> coalesced 16B vT stores. All branches block-uniform.
// Schedule per iteration (tiles t0=2i,t1=2i+1; stage t2,t3):
//   ph1: rd t0.B1->rBhi | st t2.A0 | Q00 |
//   ph2:                | st t2.B0 | Q01 | rd t0.A1->rA
//   ph3:                | st t2.B1 | Q10 | vmcnt(6)
//   ph4: rd t1.B0->rBlo | st t2.A1 | Q11 | rd t1.A0->rA
//   ph5: rd t1.B1->rBhi | st t3.A0 | Q00 |
//   ph6:                | st t3.B0 | Q01 | rd t1.A1->rA
//   ph7:                | st t3.B1 | Q10 | vmcnt(6)
//   ph8: rd t2.B0->rBlo | st t3.A1 | Q11 | rd t2.A0->rA
// vmcnt(6) leaves the 3 newest half-tiles (6 loads) in flight.
#define FENCE() asm volatile("" ::: "memory")
#define BAR() do { FENCE(); __builtin_amdgcn_s_barrier(); FENCE(); } while (0)
#define LGKM0() do { asm volatile("s_waitcnt lgkmcnt(0)" ::: "memory"); \
                     __builtin_amdgcn_sched_barrier(0); } while (0)

template<int MH, int NH>
__device__ __forceinline__ void quad_mfma(f32x4 (&acc)[2][4][2][2],
                                          const bf16x8 (&ra)[4][2],
                                          const bf16x8 (&rb)[2][2]) {
  #pragma unroll
  for (int ks = 0; ks < 2; ++ks)
    #pragma unroll
    for (int mt = 0; mt < 4; ++mt)
      #pragma unroll
      for (int nt = 0; nt < 2; ++nt)
        acc[MH][mt][NH][nt] =
          __builtin_amdgcn_mfma_f32_16x16x32_bf16(ra[mt][ks], rb[nt][ks], acc[MH][mt][NH][nt], 0, 0, 0);
}

__device__ __forceinline__ void ld_af(bf16x8 (&rr)[4][2], const u16* base,
                                      int wrow, int l16, int quad) {
  #pragma unroll
  for (int mt = 0; mt < 4; ++mt)
    #pragma unroll
    for (int ks = 0; ks < 2; ++ks)
      rr[mt][ks] = *(const bf16x8*)&base[(wrow + mt * 16 + l16) * 64 +
                                         (((ks * 4 + quad) ^ (l16 & 7)) * 8)];
}
__device__ __forceinline__ void ld_bf(bf16x8 (&rr)[2][2], const u16* base,
                                      int wrow, int l16, int quad) {
  #pragma unroll
  for (int nt = 0; nt < 2; ++nt)
    #pragma unroll
    for (int ks = 0; ks < 2; ++ks)
      rr[nt][ks] = *(const bf16x8*)&base[(wrow + nt * 16 + l16) * 64 +
                                         (((ks * 4 + quad) ^ (l16 & 7)) * 8)];
}

template<int EPI, int K, int N>
__global__ __launch_bounds__(512, 2) void gemm256_kernel(const u16* __restrict__ A,
                                                         const u16* __restrict__ W,
                                                         void* __restrict__ Cout,
                                                         const float* __restrict__ res,
                                                         u16* __restrict__ vTout) {
  __shared__ __align__(16) u16 smem[2][2][2][128 * 64];   // [buf][A/B][half] = 128 KiB
  int tid = threadIdx.x;
  int wave = tid >> 6, lane = tid & 63;
  int quad = lane >> 4, l16 = lane & 15;
  int wm = wave >> 2, wn = wave & 3;
  // XCD-chunk swizzle (bijective, all constexpr shifts): lin%8 = XCD slot
  constexpr int GX = N / 256, NB = GX * (M_ / 256), CPX = NB / 8;
  int lin = blockIdx.y * GX + blockIdx.x;
  int nlin = (lin & 7) * CPX + (lin >> 3);
  int m0 = (nlin / GX) * 256, n0 = (nlin % GX) * 256;
  constexpr int NI = (K >> 6) >> 1;   // tile-pairs; K%128==0, NI>=2

  f32x4 acc[2][4][2][2] = {};
  bf16x8 rA[4][2], rBlo[2][2], rBhi[2][2];

  // staging: 2 loads/thread per half-tile; r0=tid>>3 row, c0=tid&7 chunk
  int r0 = tid >> 3, c0 = tid & 7;
  int scb = (c0 ^ (r0 & 7)) * 16;                       // swizzled chunk, bytes
  uint32_t offA = (uint32_t)(m0 + r0) * (uint32_t)(K * 2) + (uint32_t)scb;
  uint32_t offB = (uint32_t)(n0 + r0) * (uint32_t)(K * 2) + (uint32_t)scb;

  // kof: 0 = tile t2 (even, buf0), 128 = tile t3 (odd, buf1); h adds 128 rows.
  #define STG(kof, ab, h, bufi) do {                                               \
    const char* _s = (ab) ? (const char*)W : (const char*)A;                       \
    uint32_t _o = ((ab) ? offB : offA) + (uint32_t)((kof) + (h) * (128 * K * 2));  \
    u16* _d = &smem[bufi][ab][h][wave * 512];                                      \
    gl_lds16((const u16*)(_s + _o), _d);                                           \
    gl_lds16((const u16*)(_s + _o + 64 * K * 2), _d + 4096);                       \
  } while (0)

  int wrA = wm * 64, wrB = wn * 32;

  // ---- prologue: stage t0 {A0,B0,B1,A1}, t1 {A0,B0,B1,A1}; read t0.A0/B0 ----
  STG(0, 0, 0, 0); STG(0, 1, 0, 0); STG(0, 1, 1, 0); STG(0, 0, 1, 0);
  STG(128, 0, 0, 1); STG(128, 1, 0, 1); STG(128, 1, 1, 1); STG(128, 0, 1, 1);
  offA += 256; offB += 256;                          // now points at t2
  asm volatile("s_waitcnt vmcnt(8)" ::: "memory");   // t0 fully landed
  BAR();
  ld_af(rA,   &smem[0][0][0][0], wrA, l16, quad);    // t0.A0
  ld_bf(rBlo, &smem[0][1][0][0], wrB, l16, quad);    // t0.B0
  LGKM0();
  BAR();                                             // reads done before ph1 stage

  #define G256_ITER(MORE) do {                                                     \
    /* ph1: Q00 */                                                                 \
    ld_bf(rBhi, &smem[0][1][1][0], wrB, l16, quad);                                \
    if (MORE) STG(0, 0, 0, 0);                                                     \
    BAR(); LGKM0();                                                                \
    __builtin_amdgcn_s_setprio(1); quad_mfma<0, 0>(acc, rA, rBlo);                 \
    __builtin_amdgcn_s_setprio(0); BAR();                                          \
    /* ph2: Q01, then rA <- t0.A1 */                                               \
    if (MORE) STG(0, 1, 0, 0);                                                     \
    BAR(); LGKM0();                                                                \
    __builtin_amdgcn_s_setprio(1); quad_mfma<0, 1>(acc, rA, rBhi);                 \
    __builtin_amdgcn_s_setprio(0);                                                 \
    ld_af(rA, &smem[0][0][1][0], wrA, l16, quad);                                  \
    BAR();                                                                         \
    /* ph3: Q10 | vmcnt drains t1 */                                               \
    if (MORE) STG(0, 1, 1, 0);                                                     \
    BAR(); LGKM0();                                                                \
    __builtin_amdgcn_s_setprio(1); quad_mfma<1, 0>(acc, rA, rBlo);                 \
    __builtin_amdgcn_s_setprio(0);                                                 \
    if (MORE) asm volatile("s_waitcnt vmcnt(6)" ::: "memory");                     \
    else      asm volatile("s_waitcnt vmcnt(0)" ::: "memory");                     \
    BAR();                                                                         \
    /* ph4: Q11, rBlo <- t1.B0, then rA <- t1.A0 */                                \
    ld_bf(rBlo, &smem[1][1][0][0], wrB, l16, quad);                                \
    if (MORE) STG(0, 0, 1, 0);                                                     \
    BAR(); LGKM0();                                                                \
    __builtin_amdgcn_s_setprio(1); quad_mfma<1, 1>(acc, rA, rBhi);                 \
    __builtin_amdgcn_s_setprio(0);                                                 \
    ld_af(rA, &smem[1][0][0][0], wrA, l16, quad);                                  \
    BAR();                                                                         \
    /* ph5: Q00 (t1) */                                                            \
    ld_bf(rBhi, &smem[1][1][1][0], wrB, l16, quad);                                \
    if (MORE) STG(128, 0, 0, 1);                                                   \
    BAR(); LGKM0();                                                                \
    __builtin_amdgcn_s_setprio(1); quad_mfma<0, 0>(acc, rA, rBlo);                 \
    __builtin_amdgcn_s_setprio(0); BAR();                                          \
    /* ph6: Q01, then rA <- t1.A1 */                                               \
    if (MORE) STG(128, 1, 0, 1);                                                   \
    BAR(); LGKM0();                                                                \
    __builtin_amdgcn_s_setprio(1); quad_mfma<0, 1>(acc, rA, rBhi);                 \
    __builtin_amdgcn_s_setprio(0);                                                 \
    ld_af(rA, &smem[1][0][1][0], wrA, l16, quad);                                  \
    BAR();                                                                         \
    /* ph7: Q10 | vmcnt drains t2 */                                               \
    if (MORE) STG(128, 1, 1, 1);                                                   \
    BAR(); LGKM0();                                                                \
    __builtin_amdgcn_s_setprio(1); quad_mfma<1, 0>(acc, rA, rBlo);                 \
    __builtin_amdgcn_s_setprio(0);                                                 \
    if (MORE) asm volatile("s_waitcnt vmcnt(6)" ::: "memory");                     \
    else      asm volatile("s_waitcnt vmcnt(0)" ::: "memory");                     \
    BAR();                                                                         \
    /* ph8: Q11, rBlo <- t2.B0, then rA <- t2.A0 */                                \
    if (MORE) ld_bf(rBlo, &smem[0][1][0][0], wrB, l16, quad);                      \
    if (MORE) STG(128, 0, 1, 1);                                                   \
    BAR(); LGKM0();                                                                \
    __builtin_amdgcn_s_setprio(1); quad_mfma<1, 1>(acc, rA, rBhi);                 \
    __builtin_amdgcn_s_setprio(0);                                                 \
    if (MORE) ld_af(rA, &smem[0][0][0][0], wrA, l16, quad);                        \
    BAR();                                                                         \
  } while (0)

  #pragma unroll 1
  for (int i = 0; i < NI - 1; ++i) {
    G256_ITER(true);
    offA += 256; offB += 256;
  }
  G256_ITER(false);
  #undef G256_ITER
  #undef STG

  // ---- epilogue ----
  if (EPI == 3) {
    if (n0 >= 1536) {
      // ---- v tiles: two-pass 256x128 LDS transpose -> coalesced vT stores ----
      u16* sm = &smem[0][0][0][0];
      int b = m0 >> 11, sblk = m0 & 2047;
      #pragma unroll
      for (int mh = 0; mh < 2; ++mh) {
        BAR();   // prior pass's reads (or main-loop frag reads) all retired
        #pragma unroll
        for (int mt = 0; mt < 4; ++mt) {
          int rl4 = wm * 64 + mt * 16 + quad * 4;    // local row in half, 0..127
          #pragma unroll
          for (int nh = 0; nh < 2; ++nh)
            #pragma unroll
            for (int nt = 0; nt < 2; ++nt) {
              int cl = nh * 128 + wn * 32 + nt * 16 + l16;   // local col 0..255
              ushort4 o;
              o.x = f2bf(acc[mh][mt][nh][nt][0]);
              o.y = f2bf(acc[mh][mt][nh][nt][1]);
              o.z = f2bf(acc[mh][mt][nh][nt][2]);
              o.w = f2bf(acc[mh][mt][nh][nt][3]);
              *(ushort4*)&sm[cl * 132 + rl4] = o;
            }
        }
        BAR();
        #pragma unroll
        for (int i = 0; i < 8; ++i) {
          int idx = i * 512 + tid;            // 4096: 256 cols x 16 row-chunks
          int cl = idx >> 4, c16 = idx & 15;
          uint4 d = *(const uint4*)&sm[cl * 132 + c16 * 8];
          int vg = n0 - 1536 + cl;
          int h = vg >> 6, dh = vg & 63;
          *(uint4*)&vTout[((size_t)(b * H_ + h) * 64 + dh) * (size_t)S_ +
                          sblk + mh * 128 + c16 * 8] = d;
        }
      }
    } else {
      // ---- q/k tiles: RoPE in-register (pair = adjacent lane), then store ----
      bool isq = (n0 < 768);
      float osc = isq ? 0.18033688f : 1.0f;   // q: 1/sqrt(64) * log2(e)
      bool odd = (l16 & 1);
      #pragma unroll
      for (int nt = 0; nt < 2; ++nt) {
        int kk = (((wn & 1) * 32 + nt * 16 + l16) & 63) >> 1;   // == (col&63)>>1
        float freq = exp2f(-0.41524101186092035f * (float)kk);
        #pragma unroll
        for (int mh = 0; mh < 2; ++mh)
          #pragma unroll
          for (int mt = 0; mt < 4; ++mt) {
            int gr0 = m0 + mh * 128 + wm * 64 + mt * 16 + quad * 4;
            int pos0 = gr0 & 2047;
            #pragma unroll
            for (int r = 0; r < 4; ++r) {
              float ang = (float)(pos0 + r) * freq;
              float sv, cv;
              __sincosf(ang, &sv, &cv);
              #pragma unroll
              for (int nh = 0; nh < 2; ++nh) {
                float own = acc[mh][mt][nh][nt][r];
                float pv = __shfl_xor(own, 1, 64);
                float o = odd ? (sv * pv + cv * own) : (cv * own - sv * pv);
                ((u16*)Cout)[(size_t)(gr0 + r) * N +
                             n0 + nh * 128 + wn * 32 + nt * 16 + l16] = f2bf(o * osc);
              }
            }
          }
      }
    }
  } else if (EPI == 2) {
    const int Nh = N >> 1;
    #pragma unroll
    for (int mh = 0; mh < 2; ++mh)
      #pragma unroll
      for (int mt = 0; mt < 4; ++mt)
        #pragma unroll
        for (int r = 0; r < 4; ++r) {
          int gr = m0 + mh * 128 + wm * 64 + mt * 16 + quad * 4 + r;
          #pragma unroll
          for (int nh = 0; nh < 2; ++nh) {
            float u1v = acc[mh][mt][nh][0][r], u3v = acc[mh][mt][nh][1][r];
            float sg = 1.0f / (1.0f + __builtin_amdgcn_exp2f(-u1v * 1.44269504f));
            float g = u1v * sg * u3v;
            int gc = (n0 >> 1) + nh * 64 + wn * 16 + l16;
            ((u16*)Cout)[(size_t)gr * Nh + gc] = f2bf(g);
          }
        }
  } else if (EPI == 1) {
    #pragma unroll
    for (int mh = 0; mh < 2; ++mh)
      #pragma unroll
      for (int mt = 0; mt < 4; ++mt)
        #pragma unroll
        for (int r = 0; r < 4; ++r) {
          int gr = m0 + mh * 128 + wm * 64 + mt * 16 + quad * 4 + r;
          #pragma unroll
          for (int nh = 0; nh < 2; ++nh)
            #pragma unroll
            for (int nt = 0; nt < 2; ++nt) {
              int gc = n0 + nh * 128 + wn * 32 + nt * 16 + l16;
              size_t off = (size_t)gr * N + gc;
              ((float*)Cout)[off] = acc[mh][mt][nh][nt][r] + res[off];
            }
        }
  } else {
    #pragma unroll
    for (int mh = 0; mh < 2; ++mh)
      #pragma unroll
      for (int mt = 0; mt < 4; ++mt)
        #pragma unroll
        for (int r = 0; r < 4; ++r) {
          int gr = m0 + mh * 128 + wm * 64 + mt * 16 + quad * 4 + r;
          #pragma unroll
          for (int nh = 0; nh < 2; ++nh)
            #pragma unroll
            for (int nt = 0; nt < 2; ++nt) {
              int gc = n0 + nh * 128 + wn * 32 + nt * 16 + l16;
              ((u16*)Cout)[(size_t)gr * N + gc] = f2bf(acc[mh][mt][nh][nt][r]);
            }
        }
  }
}

// ---------------- Flash attention (causal), S^T formulation, no P round-trip ------
// S^T = mfma(kf, qf) -> C-layout: key=quad*4+r, query=l16. Packed bf16 of those
// 4 regs IS the B-frag (k=quad*4+j) of a K=16 MFMA, so PV = mfma_16x16x16(vf, pf).
// Staging via global_load_lds with source-permuted chunks (same swizzle as reads).
// R3: 512-thread / 8-wave blocks, wave owns 16 queries (was 256/4w/32q).
// grid: (48 bh, 16 qt descending). block 512.
__global__ __launch_bounds__(512, 4) void attn_kernel(const u16* __restrict__ qkv,
                                                      const u16* __restrict__ vT,
                                                      u16* __restrict__ ctx) {
  __shared__ __align__(16) u16 Ks[128 * 64];   // [key][dh], physical chunk = c ^ (key&7)
  __shared__ __align__(16) u16 Vt[64 * 128];   // [dh][key], physical chunk = c ^ (dh&15)
  int bh = blockIdx.x;
  int qt = 15 - blockIdx.y;                    // LPT: biggest tiles first
  int b = bh / H_, h = bh % H_;
  const u16* qbase = qkv + (size_t)b * S_ * NQKV + h * DH_;
  const u16* kbase = qbase + 768;
  const u16* vtb   = vT + (size_t)bh * 64 * S_;
  int tid = threadIdx.x, wave = tid >> 6, lane = tid & 63;
  int quad = lane >> 4, l16 = lane & 15;
  const float MFIX = 12.0f;

  bf16x8 qf[2];
  int qrow = qt * 128 + wave * 16 + l16;
  qf[0] = *(const bf16x8*)&qbase[(size_t)qrow * NQKV + quad * 8];
  qf[1] = *(const bf16x8*)&qbase[(size_t)qrow * NQKV + 32 + quad * 8];
  f32x4 oacc[4] = {};
  float lsum = 0.f;
  int nkt = qt + 1;
  for (int kt = 0; kt < nkt; ++kt) {
    __syncthreads();
    // async staging; source chunk permuted so LDS lands pre-swizzled
    #pragma unroll
    for (int i = 0; i < 2; ++i) {
      int idx = i * 512 + tid;
      int r = idx >> 3, c = idx & 7;
      gl_lds16(&kbase[(size_t)(kt * 128 + r) * NQKV + ((c ^ (r & 7)) * 8)],
               &Ks[(i * 512 + wave * 64) * 8]);
    }
    #pragma unroll
    for (int i = 0; i < 2; ++i) {
      int idx = i * 512 + tid;
      int d = idx >> 4, c16 = idx & 15;
      gl_lds16(&vtb[(size_t)d * S_ + kt * 128 + ((c16 ^ (d & 15)) * 8)],
               &Vt[(i * 512 + wave * 64) * 8]);
    }
    __syncthreads();
    bool diag = (kt == nkt - 1);
    #pragma unroll
    for (int t = 0; t < 8; ++t) {
      if (diag && t > wave) break;   // fully-masked sub-tiles (wave-uniform)
      // S^T tile t: keys t*16..t*16+15 x 16 queries
      f32x4 sc = {};
      #pragma unroll
      for (int c = 0; c < 2; ++c) {
        bf16x8 kf = *(const bf16x8*)&Ks[(t * 16 + l16) * 64 + (((c * 4 + quad) ^ (l16 & 7)) * 8)];
        sc = __builtin_amdgcn_mfma_f32_16x16x32_bf16(kf, qf[c], sc, 0, 0, 0);
      }
      // exp2(s - MFIX), causal zeroing, per-lane l accumulation, bf16 pack
      float p[4];
      #pragma unroll
      for (int r = 0; r < 4; ++r) p[r] = __builtin_amdgcn_exp2f(sc[r] - MFIX);
      if (diag && t == wave) {
        #pragma unroll
        for (int r = 0; r < 4; ++r)
          if (quad * 4 + r > l16) p[r] = 0.f;
      }
      lsum += (p[0] + p[1]) + (p[2] + p[3]);
      uint32_t lo = ((__float_as_uint(p[0]) + 0x8000u) >> 16) |
                    ((__float_as_uint(p[1]) + 0x8000u) & 0xFFFF0000u);
      uint32_t hi = ((__float_as_uint(p[2]) + 0x8000u) >> 16) |
                    ((__float_as_uint(p[3]) + 0x8000u) & 0xFFFF0000u);
      uint2 pk; pk.x = lo; pk.y = hi;
      bf16x4 pf = *(bf16x4*)&pk;
      // PV: D[dh][query] += V^T-frag * P^T-frag, K=16
      #pragma unroll
      for (int n = 0; n < 4; ++n) {
        bf16x4 vf = *(const bf16x4*)&Vt[(n * 16 + l16) * 128 +
                                        (((t * 2 + (quad >> 1)) ^ l16) * 8) + (quad & 1) * 4];
        oacc[n] = MFMA_K16(vf, pf, oacc[n]);
      }
    }
  }
  // normalize: full l per query = reduce over the 4 quads holding its keys
  float l = lsum;
  l += __shfl_xor(l, 16, 64);
  l += __shfl_xor(l, 32, 64);
  float inv = 1.0f / l;
  #pragma unroll
  for (int n = 0; n < 4; ++n) {
    ushort4 o;
    o.x = f2bf(oacc[n][0] * inv);
    o.y = f2bf(oacc[n][1] * inv);
    o.z = f2bf(oacc[n][2] * inv);
    o.w = f2bf(oacc[n][3] * inv);
    *(ushort4*)&ctx[(size_t)(b * S_ + qrow) * D_ + h * DH_ + n * 16 + quad * 4] = o;
  }
}

// ---------------- workspace layout (bytes) ----------------
#define WQKV_OFF 0u            // 2304x768 bf16 = 3538944
#define W13_OFF  3538944u      // 4096x768 bf16 = 6291456 (interleaved)
#define W2_OFF   9830400u      // 768x2048 bf16 = 3145728
#define WO_OFF   12976128u     // 768x768 bf16  = 1179648
#define HB_OFF   14155776u     // 8192x768 bf16 = 12582912  (later: ctx)
#define QKV_OFF  26738688u     // 8192x2304 bf16 = 37748736
#define VT_OFF   64487424u     // 48x64x2048 bf16 = 12582912 (later: h2)
#define X1_OFF   77070336u     // 8192x768 fp32 = 25165824
#define G_OFF    102236160u    // 8192x2048 bf16 = 33554432 -> end 135790592

extern "C" void kernel_launch(void* const* d_in, const int* in_sizes, int n_in,
                              void* d_out, int out_size, void* d_ws, size_t ws_size,
                              hipStream_t stream) {
  const float* x    = (const float*)d_in[0];
  const float* ln1w = (const float*)d_in[1];
  const float* ln2w = (const float*)d_in[2];
  const float* pq   = (const float*)d_in[3];
  const float* pk   = (const float*)d_in[4];
  const float* pv   = (const float*)d_in[5];
  const float* po   = (const float*)d_in[6];
  const float* w1   = (const float*)d_in[7];
  const float* w2   = (const float*)d_in[8];
  const float* w3   = (const float*)d_in[9];
  char* ws = (char*)d_ws;
  u16* wqkv = (u16*)(ws + WQKV_OFF);
  u16* w13b = (u16*)(ws + W13_OFF);
  u16* w2b  = (u16*)(ws + W2_OFF);
  u16* wob  = (u16*)(ws + WO_OFF);
  u16* hb   = (u16*)(ws + HB_OFF);
  u16* qkvb = (u16*)(ws + QKV_OFF);
  u16* vtb  = (u16*)(ws + VT_OFF);
  u16* cb   = (u16*)(ws + HB_OFF);   // alias hb (dead after QKV GEMM)
  float* x1 = (float*)(ws + X1_OFF);
  u16* h2b  = (u16*)(ws + VT_OFF);   // alias vT (dead after attn)
  u16* gb   = (u16*)(ws + G_OFF);

  // weights -> bf16 (2 launches)
  cast_all_kernel<<<3840, 256, 0, stream>>>(pq, pk, pv, po, w2, wqkv, wob, w2b);
  cast_w13_kernel<<<dim3(2048, 2), 192, 0, stream>>>(w1, w3, w13b);

  // attention sublayer
  rmsnorm_kernel<<<M_, 256, 0, stream>>>(x, ln1w, hb);
  // QKV GEMM: 256x256 8-phase with fused RoPE/vT epilogue (R9; was gemm_bt<128,3>)
  gemm256_kernel<3, 768, NQKV><<<dim3(NQKV / 256, M_ / 256), 512, 0, stream>>>(hb, wqkv, qkvb, nullptr, vtb);
  // attn: 8-wave blocks (R3 occupancy fix)
  attn_kernel<<<dim3(48, 16), 512, 0, stream>>>(qkvb, vtb, cb);
  gemm_bt_kernel<64, 1><<<dim3(6, 128), 256, 0, stream>>>(cb, wob, x1, x, nullptr, 768, 768);

  // FFN sublayer
  rmsnorm_kernel<<<M_, 256, 0, stream>>>(x1, ln2w, h2b);
  // W13 GEMM: 256x256 8-phase + XCD swizzle (R7 form; R8 persistent reverted)
  gemm256_kernel<2, 768, N13><<<dim3(N13 / 256, M_ / 256), 512, 0, stream>>>(h2b, w13b, gb, nullptr, nullptr);
  gemm_bt_kernel<64, 1><<<dim3(6, 128), 256, 0, stream>>>(gb, w2b, (float*)d_out, x1, nullptr, 2048, 768);
}